// Round 8
// baseline (703.524 us; speedup 1.0000x reference)
//
#include <hip/hip_runtime.h>
#include <hip/hip_bf16.h>

// ---------- types ----------
typedef __attribute__((ext_vector_type(8))) short short8;
typedef __attribute__((ext_vector_type(4))) float f32x4;

#define MROWS 4096      // b*l
#define CDIM  1024
#define HEADS 16
#define DHEAD 64
#define NSEQ  1024

// ---------- small device helpers ----------
__device__ inline float softw(const float* __restrict__ w, int idx) {
    float m = w[0];
#pragma unroll
    for (int i = 1; i < 6; i++) m = fmaxf(m, w[i]);
    float s = 0.f, v = 0.f;
#pragma unroll
    for (int i = 0; i < 6; i++) {
        float e = __expf((w[i] - m) * 100.0f);
        s += e;
        if (i == idx) v = e;
    }
    return v / s;
}

__device__ inline float gelu_f(float x) {
    return 0.5f * x * (1.0f + erff(x * 0.70710678118654752f));
}

// ---------- fused prep: all weight converts + x->bf16 + amacc zero ----------
// segment sizes (elements): conv 1M | mlp1 4M | qkv 3M | proj 1M | mlp2 4M | x 4M
#define S0 1048576ULL
#define S1 (S0 + 4194304ULL)
#define S2 (S1 + 3145728ULL)
#define S3 (S2 + 1048576ULL)
#define S4 (S3 + 4194304ULL)
#define S5 (S4 + 4194304ULL)

__global__ __launch_bounds__(256) void prep_all(
    const float* __restrict__ conv_w, const float* __restrict__ mlp1_w,
    const float* __restrict__ qkv_w, const float* __restrict__ proj_w,
    const float* __restrict__ mlp2_w, const float* __restrict__ x_list,
    __hip_bfloat16* __restrict__ wcat, __hip_bfloat16* __restrict__ qkvwb,
    __hip_bfloat16* __restrict__ projwb, __hip_bfloat16* __restrict__ mlp2wb,
    __hip_bfloat16* __restrict__ xb, float* __restrict__ amacc)
{
    size_t gid = (size_t)blockIdx.x * 256 + threadIdx.x;
    if (gid < 4096) amacc[gid] = 0.f;
    size_t i = gid * 4;
    if (i >= S5) return;
    float4 v;
    __hip_bfloat16* d;
    if (i < S4) {
        const float* src;
        if (i < S0)      { src = conv_w + i;        d = wcat + i; }
        else if (i < S1) { src = mlp1_w + (i - S0); d = wcat + i; }
        else if (i < S2) { src = qkv_w + (i - S1);  d = qkvwb + (i - S1); }
        else if (i < S3) { src = proj_w + (i - S2); d = projwb + (i - S2); }
        else             { src = mlp2_w + (i - S3); d = mlp2wb + (i - S3); }
        v = *(const float4*)src;
    } else {
        size_t j = i - S4;
        const float4* xp = (const float4*)(x_list + 2 * j);
        float4 a = xp[0], b = xp[1];
        v.x = a.y; v.y = a.w; v.z = b.y; v.w = b.w;
        d = xb + j;
    }
    d[0] = __float2bfloat16(v.x);
    d[1] = __float2bfloat16(v.y);
    d[2] = __float2bfloat16(v.z);
    d[3] = __float2bfloat16(v.w);
}

// ---------- bf16 MFMA GEMM, dbuf LDS + depth-2 register prefetch ----------
// Manually 2x-unrolled K-loop: ALL private arrays statically indexed
// (dynamic indices spill staging to scratch: 28x slower, round 5).
// EPI: 1=fused conv+mlp1 (col<1024: base mix from x_list + w2*gelu -> xmixb bf16;
//                         col>=1024: gelu -> hb bf16)
//      3=mlp2 (xmixb += w5*v, bf16 rmw), 4=proj (+bias+residual(bf16) -> f0 f32),
//      5=qkv (fused per-head LN: q->b1, k->b2 bf16 [b,h,n,d]; v->b0 V^T bf16)
#define BKT 32
#define LDA 40   // 32 + 8 pad (16B aligned, 2-way LDS banks = free)

template<int EPI, int FM, int FN>
__global__ __launch_bounds__(256) void gemm_bf16(
    const __hip_bfloat16* __restrict__ A, const __hip_bfloat16* __restrict__ W,
    const float* __restrict__ bias,
    float* __restrict__ f0, const float* __restrict__ f1,
    __hip_bfloat16* __restrict__ b0, __hip_bfloat16* __restrict__ b1,
    __hip_bfloat16* __restrict__ b2,
    const float* __restrict__ g0, const float* __restrict__ be0,
    const float* __restrict__ g1, const float* __restrict__ be1,
    const float* __restrict__ wvec, int M, int N, int K)
{
    constexpr int BMt = FM * 32;
    constexpr int BNt = FN * 32;
    constexpr int NA = BMt / 64;    // short8 staged per thread (A)
    constexpr int NB = BNt / 64;    // short8 staged per thread (B)
    __shared__ __hip_bfloat16 As[2][BMt * LDA];
    __shared__ __hip_bfloat16 Bs[2][BNt * LDA];
    int t = threadIdx.x;
    int n0 = blockIdx.x * BNt, m0 = blockIdx.y * BMt;
    int wave = t >> 6, lane = t & 63;
    int wr = wave >> 1, wc = wave & 1;
    int quad = lane >> 4, l16 = lane & 15;
    int r0 = t >> 2, c0 = (t & 3) * 8;    // staging: 4 lanes/row, 64 rows/round

    short8 sa0[NA], sb0[NB], sa1[NA], sb1[NB];
    auto ldg = [&](int k0, short8* da, short8* db) {
#pragma unroll
        for (int i = 0; i < NA; i++)
            da[i] = *(const short8*)(A + (size_t)(m0 + r0 + 64 * i) * K + k0 + c0);
#pragma unroll
        for (int i = 0; i < NB; i++)
            db[i] = *(const short8*)(W + (size_t)(n0 + r0 + 64 * i) * K + k0 + c0);
    };
    ldg(0, sa0, sb0);
    ldg(BKT, sa1, sb1);

    f32x4 zero = {0.f, 0.f, 0.f, 0.f};
    f32x4 acc[FM][FN];
#pragma unroll
    for (int i = 0; i < FM; i++)
#pragma unroll
        for (int j = 0; j < FN; j++) acc[i][j] = zero;

    for (int k0 = 0; k0 < K; k0 += 2 * BKT) {
        // ---- even half: buffer 0 ----
#pragma unroll
        for (int i = 0; i < NA; i++)
            *(short8*)&As[0][(r0 + 64 * i) * LDA + c0] = sa0[i];
#pragma unroll
        for (int i = 0; i < NB; i++)
            *(short8*)&Bs[0][(r0 + 64 * i) * LDA + c0] = sb0[i];
        __syncthreads();
        if (k0 + 2 * BKT < K) ldg(k0 + 2 * BKT, sa0, sb0);
        {
            short8 af[FM], bf[FN];
#pragma unroll
            for (int i = 0; i < FM; i++)
                af[i] = *(const short8*)&As[0][(wr * FM * 16 + i * 16 + l16) * LDA + quad * 8];
#pragma unroll
            for (int j = 0; j < FN; j++)
                bf[j] = *(const short8*)&Bs[0][(wc * FN * 16 + j * 16 + l16) * LDA + quad * 8];
#pragma unroll
            for (int i = 0; i < FM; i++)
#pragma unroll
                for (int j = 0; j < FN; j++)
                    acc[i][j] = __builtin_amdgcn_mfma_f32_16x16x32_bf16(
                        af[i], bf[j], acc[i][j], 0, 0, 0);
        }
        // ---- odd half: buffer 1 ----
#pragma unroll
        for (int i = 0; i < NA; i++)
            *(short8*)&As[1][(r0 + 64 * i) * LDA + c0] = sa1[i];
#pragma unroll
        for (int i = 0; i < NB; i++)
            *(short8*)&Bs[1][(r0 + 64 * i) * LDA + c0] = sb1[i];
        __syncthreads();
        if (k0 + 3 * BKT < K) ldg(k0 + 3 * BKT, sa1, sb1);
        {
            short8 af[FM], bf[FN];
#pragma unroll
            for (int i = 0; i < FM; i++)
                af[i] = *(const short8*)&As[1][(wr * FM * 16 + i * 16 + l16) * LDA + quad * 8];
#pragma unroll
            for (int j = 0; j < FN; j++)
                bf[j] = *(const short8*)&Bs[1][(wc * FN * 16 + j * 16 + l16) * LDA + quad * 8];
#pragma unroll
            for (int i = 0; i < FM; i++)
#pragma unroll
                for (int j = 0; j < FN; j++)
                    acc[i][j] = __builtin_amdgcn_mfma_f32_16x16x32_bf16(
                        af[i], bf[j], acc[i][j], 0, 0, 0);
        }
    }

    if constexpr (EPI == 1) {
        // fused conv (cols 0..1023) + mlp1 (cols 1024..5119). Wave col-span is a
        // multiple of 64 and never straddles 1024 -> wave-uniform branch.
        float wmx = softw(wvec, 2);
        float w0c = softw(wvec, 0);
        float w14c = softw(wvec, 1) + softw(wvec, 4);
        int colbase = n0 + wc * FN * 16;
        bool isconv = colbase < 1024;
#pragma unroll
        for (int i = 0; i < FM; i++) {
#pragma unroll
            for (int j = 0; j < FN; j++) {
                int col = colbase + j * 16 + l16;
                float bv = isconv ? bias[col] : be0[col - 1024];
#pragma unroll
                for (int r = 0; r < 4; r++) {
                    int row = m0 + wr * FM * 16 + i * 16 + quad * 4 + r;
                    float v = acc[i][j][r] + bv;
                    if (isconv) {
                        size_t idx = (size_t)row * 1024 + col;
                        float2 xl = ((const float2*)f1)[idx];
                        b0[idx] = __float2bfloat16(
                            w0c * xl.x + w14c * xl.y + wmx * gelu_f(v));
                    } else {
                        b1[(size_t)row * 4096 + (col - 1024)] =
                            __float2bfloat16(gelu_f(v));
                    }
                }
            }
        }
        return;
    }

    if constexpr (EPI == 5) {
        int colbase = n0 + wc * FN * 16;           // 64-aligned => one head per wave
        int portion = colbase >> 10;               // 0=q 1=k 2=v
        int hh = (colbase >> 6) & 15;
        float bv[FN];
#pragma unroll
        for (int j = 0; j < FN; j++) bv[j] = bias[colbase + j * 16 + l16];
        if (portion == 2) {
#pragma unroll
            for (int i = 0; i < FM; i++)
#pragma unroll
                for (int j = 0; j < FN; j++)
#pragma unroll
                    for (int r = 0; r < 4; r++) {
                        int row = m0 + wr * FM * 16 + i * 16 + quad * 4 + r;
                        int bb = row >> 10, nn = row & 1023;
                        int dd = j * 16 + l16;
                        b0[((size_t)(bb * 16 + hh) * DHEAD + dd) * NSEQ + nn] =
                            __float2bfloat16(acc[i][j][r] + bv[j]);
                    }
        } else {
            const float* g  = (portion == 0) ? g0 : g1;
            const float* be = (portion == 0) ? be0 : be1;
            __hip_bfloat16* dst = (portion == 0) ? b1 : b2;
            float gv[FN], bev[FN];
#pragma unroll
            for (int j = 0; j < FN; j++) {
                gv[j] = g[j * 16 + l16];
                bev[j] = be[j * 16 + l16];
            }
#pragma unroll
            for (int i = 0; i < FM; i++)
#pragma unroll
                for (int r = 0; r < 4; r++) {
                    float s1 = 0.f, s2 = 0.f;
#pragma unroll
                    for (int j = 0; j < FN; j++) {
                        float v = acc[i][j][r] + bv[j];
                        s1 += v; s2 += v * v;
                    }
#pragma unroll
                    for (int mk = 1; mk < 16; mk <<= 1) {
                        s1 += __shfl_xor(s1, mk, 64);
                        s2 += __shfl_xor(s2, mk, 64);
                    }
                    float mean = s1 * (1.f / 64.f);
                    float var = s2 * (1.f / 64.f) - mean * mean;
                    float rs = rsqrtf(var + 1e-5f);
                    int row = m0 + wr * FM * 16 + i * 16 + quad * 4 + r;
                    int bb = row >> 10, nn = row & 1023;
                    size_t base = ((size_t)(bb * 16 + hh) * NSEQ + nn) * DHEAD;
#pragma unroll
                    for (int j = 0; j < FN; j++)
                        dst[base + j * 16 + l16] = __float2bfloat16(
                            (acc[i][j][r] + bv[j] - mean) * rs * gv[j] + bev[j]);
                }
        }
        return;
    }

    float wmx = 0.f;
    if (EPI == 3) wmx = softw(wvec, 5);

#pragma unroll
    for (int i = 0; i < FM; i++) {
#pragma unroll
        for (int j = 0; j < FN; j++) {
            int col = n0 + wc * FN * 16 + j * 16 + l16;
            float bv = bias[col];
#pragma unroll
            for (int r = 0; r < 4; r++) {
                int row = m0 + wr * FM * 16 + i * 16 + quad * 4 + r;
                float v = acc[i][j][r] + bv;
                size_t idx = (size_t)row * N + col;
                if (EPI == 3) {
                    float tv = __bfloat162float(b0[idx]) + wmx * v;
                    b0[idx] = __float2bfloat16(tv);
                } else if (EPI == 4) {
                    f0[idx] = v + __bfloat162float(b1[idx]);  // proj + residual
                }
            }
        }
    }
}

// ---------- fused channel attention: ca1 (relu fc) + ca2 (sigmoid gate rmw) ----
// 256 blocks x 16 rows. Phase 1 keeps h in LDS; phase 2 streams ca2_w chunks.
__global__ __launch_bounds__(256) void ca_fused(
    const __hip_bfloat16* __restrict__ xb, const float* __restrict__ w1,
    const float* __restrict__ b1, const float* __restrict__ w2,
    const float* __restrict__ b2, __hip_bfloat16* __restrict__ xmixb,
    const float* __restrict__ wvec)
{
    __shared__ float S[16640 + 16 * 64];   // Wt area (phase2) reused by Xs/Ws; hs at tail
    float* Xs = S;                 // [16*65]
    float* Ws = S + 1040;          // [64*65]
    float* hs = S + 16640;         // [16*64]
    float* Wt = S;                 // [256*65] (phase 2)
    int t = threadIdx.x;
    int m0 = blockIdx.x * 16;
    int row = t >> 4, cg = t & 15;
    float acc1[4] = {0.f, 0.f, 0.f, 0.f};
    for (int k0 = 0; k0 < 1024; k0 += 64) {
#pragma unroll
        for (int i = 0; i < 4; i++) {
            int e = t + i * 256; int r = e >> 6, c = e & 63;
            Xs[r * 65 + c] = __bfloat162float(xb[(size_t)(m0 + r) * 1024 + k0 + c]);
        }
#pragma unroll
        for (int i = 0; i < 16; i++) {
            int e = t + i * 256; int r = e >> 6, c = e & 63;
            Ws[r * 65 + c] = w1[(size_t)r * 1024 + k0 + c];
        }
        __syncthreads();
        for (int k = 0; k < 64; k++) {
            float xv = Xs[row * 65 + k];
#pragma unroll
            for (int c = 0; c < 4; c++)
                acc1[c] += xv * Ws[(cg * 4 + c) * 65 + k];
        }
        __syncthreads();
    }
#pragma unroll
    for (int c = 0; c < 4; c++)
        hs[row * 64 + cg * 4 + c] = fmaxf(acc1[c] + b1[cg * 4 + c], 0.f);

    float w3 = softw(wvec, 3);
    for (int n0 = 0; n0 < 1024; n0 += 256) {
        __syncthreads();   // hs visible (first pass) / prior Wt reads done
#pragma unroll
        for (int i = 0; i < 64; i++) {
            int e = t + i * 256; int r = e >> 6, c = e & 63;
            Wt[r * 65 + c] = w2[(size_t)(n0 + r) * 64 + c];
        }
        __syncthreads();
        int n = n0 + t;
        float bv = b2[n];
        float acc[16];
#pragma unroll
        for (int mi = 0; mi < 16; mi++) acc[mi] = bv;
        for (int k = 0; k < 64; k++) {
            float wv = Wt[t * 65 + k];
#pragma unroll
            for (int mi = 0; mi < 16; mi++) acc[mi] += hs[mi * 64 + k] * wv;
        }
#pragma unroll
        for (int mi = 0; mi < 16; mi++) {
            size_t idx = (size_t)(m0 + mi) * 1024 + n;
            float sg = 1.f / (1.f + __expf(-acc[mi]));
            float cur = __bfloat162float(xmixb[idx]);
            xmixb[idx] = __float2bfloat16(cur + w3 * sg * __bfloat162float(xb[idx]));
        }
    }
}

// ---------- MFMA flash attention ----------
#define PSTR 72   // bf16 stride: 144 B, 16B-aligned, 2-way banks
__global__ __launch_bounds__(256) void flash_mfma(
    const __hip_bfloat16* __restrict__ qb, const __hip_bfloat16* __restrict__ kb,
    const __hip_bfloat16* __restrict__ vt, __hip_bfloat16* __restrict__ ao)
{
    __shared__ __hip_bfloat16 Plds[4][32 * PSTR];
    int bh = blockIdx.x;
    int i0 = blockIdx.y * 128;
    int b = bh >> 4, h = bh & 15;
    int t = threadIdx.x, wave = t >> 6, lane = t & 63;
    int l16 = lane & 15, quad = lane >> 4;
    const __hip_bfloat16* qbase = qb + (size_t)bh * NSEQ * DHEAD;
    const __hip_bfloat16* kbase = kb + (size_t)bh * NSEQ * DHEAD;
    const __hip_bfloat16* vbase = vt + (size_t)bh * DHEAD * NSEQ;
    __hip_bfloat16* pw = Plds[wave];
    int qrow0 = i0 + wave * 32;

    short8 aq[2][2];
#pragma unroll
    for (int ri = 0; ri < 2; ri++)
#pragma unroll
        for (int ks = 0; ks < 2; ks++)
            aq[ri][ks] = *(const short8*)(qbase +
                (size_t)(qrow0 + ri * 16 + l16) * DHEAD + ks * 32 + quad * 8);

    f32x4 zero = {0.f, 0.f, 0.f, 0.f};
    f32x4 o[2][4];
    float mrow[2][4], lrow[2][4];
#pragma unroll
    for (int ri = 0; ri < 2; ri++) {
#pragma unroll
        for (int nt = 0; nt < 4; nt++) o[ri][nt] = zero;
#pragma unroll
        for (int rr = 0; rr < 4; rr++) { mrow[ri][rr] = -1e30f; lrow[ri][rr] = 0.f; }
    }

    for (int j0 = 0; j0 < NSEQ; j0 += 64) {
        short8 bk[4][2];
#pragma unroll
        for (int jt = 0; jt < 4; jt++)
#pragma unroll
            for (int ks = 0; ks < 2; ks++)
                bk[jt][ks] = *(const short8*)(kbase +
                    (size_t)(j0 + jt * 16 + l16) * DHEAD + ks * 32 + quad * 8);
        short8 bv[4][2];
#pragma unroll
        for (int nt = 0; nt < 4; nt++)
#pragma unroll
            for (int ks = 0; ks < 2; ks++)
                bv[nt][ks] = *(const short8*)(vbase +
                    (size_t)(nt * 16 + l16) * NSEQ + j0 + ks * 32 + quad * 8);

#pragma unroll
        for (int ri = 0; ri < 2; ri++) {
            f32x4 s[4];
#pragma unroll
            for (int jt = 0; jt < 4; jt++) s[jt] = zero;
#pragma unroll
            for (int jt = 0; jt < 4; jt++)
#pragma unroll
                for (int ks = 0; ks < 2; ks++)
                    s[jt] = __builtin_amdgcn_mfma_f32_16x16x32_bf16(
                        aq[ri][ks], bk[jt][ks], s[jt], 0, 0, 0);
#pragma unroll
            for (int rr = 0; rr < 4; rr++) {
                float mx = -1e30f;
#pragma unroll
                for (int jt = 0; jt < 4; jt++) {
                    s[jt][rr] *= 0.125f;
                    mx = fmaxf(mx, s[jt][rr]);
                }
#pragma unroll
                for (int mk = 1; mk < 16; mk <<= 1) mx = fmaxf(mx, __shfl_xor(mx, mk, 64));
                float om = mrow[ri][rr];
                float nm = fmaxf(om, mx);
                float al = __expf(om - nm);
                mrow[ri][rr] = nm;
                float ss = 0.f;
#pragma unroll
                for (int jt = 0; jt < 4; jt++) {
                    float p = __expf(s[jt][rr] - nm);
                    pw[(ri * 16 + quad * 4 + rr) * PSTR + jt * 16 + l16] =
                        __float2bfloat16(p);
                    ss += p;
                }
#pragma unroll
                for (int mk = 1; mk < 16; mk <<= 1) ss += __shfl_xor(ss, mk, 64);
                lrow[ri][rr] = lrow[ri][rr] * al + ss;
#pragma unroll
                for (int nt = 0; nt < 4; nt++) o[ri][nt][rr] *= al;
            }
        }
#pragma unroll
        for (int ri = 0; ri < 2; ri++) {
            short8 ap[2];
#pragma unroll
            for (int ks = 0; ks < 2; ks++)
                ap[ks] = *(const short8*)&pw[(ri * 16 + l16) * PSTR + ks * 32 + quad * 8];
#pragma unroll
            for (int nt = 0; nt < 4; nt++)
#pragma unroll
                for (int ks = 0; ks < 2; ks++)
                    o[ri][nt] = __builtin_amdgcn_mfma_f32_16x16x32_bf16(
                        ap[ks], bv[nt][ks], o[ri][nt], 0, 0, 0);
        }
    }

#pragma unroll
    for (int ri = 0; ri < 2; ri++)
#pragma unroll
        for (int rr = 0; rr < 4; rr++) {
            float inv = 1.f / lrow[ri][rr];
            int row = qrow0 + ri * 16 + quad * 4 + rr;
#pragma unroll
            for (int nt = 0; nt < 4; nt++)
                ao[((size_t)b * NSEQ + row) * CDIM + h * 64 + nt * 16 + l16] =
                    __float2bfloat16(o[ri][nt][rr] * inv);
        }
}

// ---------- attn_map: mean over heads of attn[:,0,1:] ----------
__global__ __launch_bounds__(256) void attn_map_acc(
    const __hip_bfloat16* __restrict__ qf, const __hip_bfloat16* __restrict__ kf,
    float* __restrict__ am)
{
    __shared__ float q0[64];
    __shared__ float red[256];
    int bh = blockIdx.x, t = threadIdx.x;
    const __hip_bfloat16* qr = qf + (size_t)bh * NSEQ * DHEAD;
    const __hip_bfloat16* kb = kf + (size_t)bh * NSEQ * DHEAD;
    if (t < 64) q0[t] = __bfloat162float(qr[t]);
    __syncthreads();
    float s[4];
    float mx = -1e30f;
#pragma unroll
    for (int ji = 0; ji < 4; ji++) {
        int j = ji * 256 + t;
        float a = 0.f;
        for (int k = 0; k < 64; k++) a += q0[k] * __bfloat162float(kb[(size_t)j * 64 + k]);
        a *= 0.125f;
        s[ji] = a;
        mx = fmaxf(mx, a);
    }
    red[t] = mx; __syncthreads();
    for (int st = 128; st > 0; st >>= 1) {
        if (t < st) red[t] = fmaxf(red[t], red[t + st]);
        __syncthreads();
    }
    float M = red[0]; __syncthreads();
    float sum = 0.f;
#pragma unroll
    for (int ji = 0; ji < 4; ji++) { s[ji] = __expf(s[ji] - M); sum += s[ji]; }
    red[t] = sum; __syncthreads();
    for (int st = 128; st > 0; st >>= 1) {
        if (t < st) red[t] += red[t + st];
        __syncthreads();
    }
    float inv = 1.f / red[0];
    int b = bh >> 4;
#pragma unroll
    for (int ji = 0; ji < 4; ji++) {
        int j = ji * 256 + t;
        if (j > 0) atomicAdd(&am[b * 1024 + j], s[ji] * inv * (1.f / 16.f));
    }
}

__global__ __launch_bounds__(256) void attn_map_out(
    const float* __restrict__ am, float* __restrict__ out1)
{
    int i = blockIdx.x * 256 + threadIdx.x;
    if (i < 4 * 1023) {
        int b = i / 1023;
        int j = i - b * 1023 + 1;
        out1[i] = am[b * 1024 + j];
    }
}

// ---------- launch ----------
extern "C" void kernel_launch(void* const* d_in, const int* in_sizes, int n_in,
                              void* d_out, int out_size, void* d_ws, size_t ws_size,
                              hipStream_t stream)
{
    const float* x_list = (const float*)d_in[0];
    const float* wvec   = (const float*)d_in[1];
    const float* qkv_w  = (const float*)d_in[2];
    const float* qkv_b  = (const float*)d_in[3];
    const float* proj_w = (const float*)d_in[4];
    const float* proj_b = (const float*)d_in[5];
    const float* nq_g   = (const float*)d_in[6];
    const float* nq_b   = (const float*)d_in[7];
    const float* nk_g   = (const float*)d_in[8];
    const float* nk_b   = (const float*)d_in[9];
    const float* conv_w = (const float*)d_in[10];
    const float* conv_b = (const float*)d_in[11];
    const float* ca1_w  = (const float*)d_in[12];
    const float* ca1_b  = (const float*)d_in[13];
    const float* ca2_w  = (const float*)d_in[14];
    const float* ca2_b  = (const float*)d_in[15];
    const float* mlp1_w = (const float*)d_in[16];
    const float* mlp1_b = (const float*)d_in[17];
    const float* mlp2_w = (const float*)d_in[18];
    const float* mlp2_b = (const float*)d_in[19];

    float* out0 = (float*)d_out;
    float* out1 = out0 + (size_t)4 * 1024 * 1024;

    char* ws = (char*)d_ws;
    size_t off = 0;
    auto alloc = [&](size_t bytes) -> char* {
        char* p = ws + off;
        off += (bytes + 255) & ~(size_t)255;
        return p;
    };
    __hip_bfloat16* xb     = (__hip_bfloat16*)alloc((size_t)MROWS * CDIM * 2);
    __hip_bfloat16* xmixb  = (__hip_bfloat16*)alloc((size_t)MROWS * CDIM * 2);
    __hip_bfloat16* hb     = (__hip_bfloat16*)alloc((size_t)MROWS * 4096 * 2);
    __hip_bfloat16* qbb    = (__hip_bfloat16*)alloc((size_t)MROWS * CDIM * 2);
    __hip_bfloat16* kbb    = (__hip_bfloat16*)alloc((size_t)MROWS * CDIM * 2);
    __hip_bfloat16* vtb    = (__hip_bfloat16*)alloc((size_t)MROWS * CDIM * 2);
    __hip_bfloat16* aob    = (__hip_bfloat16*)alloc((size_t)MROWS * CDIM * 2);
    float*          amacc  = (float*)alloc(4096 * 4);
    __hip_bfloat16* wcat   = (__hip_bfloat16*)alloc((size_t)5120 * 1024 * 2);  // conv|mlp1
    __hip_bfloat16* qkvwb  = (__hip_bfloat16*)alloc((size_t)3145728 * 2);
    __hip_bfloat16* projwb = (__hip_bfloat16*)alloc((size_t)1048576 * 2);
    __hip_bfloat16* mlp2wb = (__hip_bfloat16*)alloc((size_t)4194304 * 2);

    // fused prep: all weight converts + x->bf16 + amacc zero (17.8M elems / 4)
    prep_all<<<17408, 256, 0, stream>>>(
        conv_w, mlp1_w, qkv_w, proj_w, mlp2_w, x_list,
        wcat, qkvwb, projwb, mlp2wb, xb, amacc);

    // fused conv+mlp1 (FM4/FN8 = 128x256 tile): cols<1024 -> xmixb, else -> hb
    gemm_bf16<1, 4, 8><<<dim3(20, 32), 256, 0, stream>>>(
        xb, wcat, conv_b, nullptr, x_list, xmixb, hb, nullptr,
        nullptr, mlp1_b, nullptr, nullptr, wvec, MROWS, 5120, 1024);

    // fused channel attention: xmixb += w3*sig(fc2(relu(fc1 x)))*x
    ca_fused<<<256, 256, 0, stream>>>(xb, ca1_w, ca1_b, ca2_w, ca2_b, xmixb, wvec);

    // mlp2: xmixb += w5*(hb @ mlp2_w^T + b) (bf16 rmw)
    gemm_bf16<3, 4, 4><<<dim3(8, 32), 256, 0, stream>>>(
        hb, mlp2wb, mlp2_b, nullptr, nullptr, xmixb, nullptr, nullptr,
        nullptr, nullptr, nullptr, nullptr, wvec, MROWS, 1024, 4096);

    // qkv with fused per-head LN: q->qbb, k->kbb bf16 [b,h,n,d]; v->V^T bf16
    gemm_bf16<5, 4, 4><<<dim3(24, 32), 256, 0, stream>>>(
        xmixb, qkvwb, qkv_b, nullptr, nullptr, vtb, qbb, kbb,
        nq_g, nq_b, nk_g, nk_b, wvec, MROWS, 3072, 1024);

    // attention (MFMA)
    flash_mfma<<<dim3(64, 8), 256, 0, stream>>>(qbb, kbb, vtb, aob);

    // attn_map
    attn_map_acc<<<64, 256, 0, stream>>>(qbb, kbb, amacc);
    attn_map_out<<<16, 256, 0, stream>>>(amacc, out1);

    // projection + residual (residual from xmixb bf16)
    gemm_bf16<4, 4, 4><<<dim3(8, 32), 256, 0, stream>>>(
        aob, projwb, proj_b, out0, nullptr, nullptr, xmixb, nullptr,
        nullptr, nullptr, nullptr, nullptr, wvec, MROWS, 1024, 1024);
}